// Round 5
// baseline (490.679 us; speedup 1.0000x reference)
//
#include <hip/hip_runtime.h>
#include <hip/hip_bf16.h>
#include <math.h>

typedef __hip_bfloat16 bf16;
typedef __bf16  bf16x8  __attribute__((ext_vector_type(8)));
typedef float   floatx4 __attribute__((ext_vector_type(4)));

typedef const __attribute__((address_space(1))) void global_cv_t;
typedef __attribute__((address_space(3))) void       lds_v_t;

static __device__ __forceinline__ float bf2f(bf16 h) { return __bfloat162float(h); }
static __device__ __forceinline__ bf16  f2bf(float f) { return __float2bfloat16(f); }

__device__ __forceinline__ void load_lds16(const void* g, void* l) {
    __builtin_amdgcn_global_load_lds((global_cv_t*)g, (lds_v_t*)l, 16, 0, 0);
}

// Packed-A layout ("fragment order"): for logical A[M][K] (K=1024), the
// 16-row tile mt, 32-k block kb stores granule (quad*16 + l16, 8 elems) at
//   A_p[ mt*16384 + kb*512 + (quad*16 + l16)*8 + j ]
// where m = mt*16 + l16, k = kb*32 + quad*8 + j.  An MFMA A-fragment load is
// then exactly lane*16B contiguous -> one global_load_dwordx4 per wave.
__device__ __forceinline__ size_t paddr(int m, int k) {
    return ((size_t)(m >> 4) << 14) + ((size_t)(k >> 5) << 9)
         + (((k >> 3) & 3) << 7) + ((m & 15) << 3) + (k & 7);
}

// ---------------------------------------------------------------------------
// x (f32) -> packed bf16. Block: 16 rows x 256 k. Grid (1024, 4).
// ---------------------------------------------------------------------------
__global__ __launch_bounds__(256) void packx_k(const float* __restrict__ in,
                                               bf16* __restrict__ out)
{
    __shared__ float t[16][260];
    const int mt  = blockIdx.x;
    const int k0  = blockIdx.y << 8;
    const int tid = threadIdx.x;
    const float* src = in + ((size_t)mt << 14) + k0;
#pragma unroll
    for (int j = 0; j < 4; ++j) {
        const int idx = j * 256 + tid;            // 0..1023
        const int r = idx >> 6, c4 = (idx & 63) << 2;
        const float4 v = *(const float4*)(src + (size_t)r * 1024 + c4);
        t[r][c4] = v.x; t[r][c4 + 1] = v.y; t[r][c4 + 2] = v.z; t[r][c4 + 3] = v.w;
    }
    __syncthreads();
    bf16* dst = out + ((size_t)mt << 14) + ((size_t)(k0 >> 5) << 9);
#pragma unroll
    for (int j = 0; j < 2; ++j) {
        const int g = j * 256 + tid;              // granule 0..511
        const int r = g & 15, quad = (g >> 4) & 3, kb = g >> 6;
        const float* s = &t[r][kb * 32 + quad * 8];
        union { bf16x8 v; bf16 h[8]; } u;
#pragma unroll
        for (int e = 0; e < 8; ++e) u.h[e] = f2bf(s[e]);
        *(bf16x8*)(dst + ((size_t)kb << 9) + ((quad * 16 + r) << 3)) = u.v;
    }
}

// ---------------------------------------------------------------------------
// Transpose+convert 5x (1024x1024 f32): dst[n][k] = (bf16)src[k][n]
// ---------------------------------------------------------------------------
__global__ __launch_bounds__(256) void trc_k(
    const float* __restrict__ w0, const float* __restrict__ w1,
    const float* __restrict__ w2, const float* __restrict__ w3,
    const float* __restrict__ w4, bf16* __restrict__ dst)
{
    const float* src;
    switch (blockIdx.z) {
        case 0: src = w0; break;
        case 1: src = w1; break;
        case 2: src = w2; break;
        case 3: src = w3; break;
        default: src = w4; break;
    }
    bf16* d = dst + ((size_t)blockIdx.z << 20);
    __shared__ float tile[32][33];
    const int tx = threadIdx.x & 31;
    const int ty = threadIdx.x >> 5;   // 0..7
    const int bx = blockIdx.x * 32, by = blockIdx.y * 32;
#pragma unroll
    for (int j = 0; j < 32; j += 8)
        tile[ty + j][tx] = src[(size_t)(by + ty + j) * 1024 + bx + tx];
    __syncthreads();
#pragma unroll
    for (int j = 0; j < 32; j += 8)
        d[(size_t)(bx + ty + j) * 1024 + by + tx] = f2bf(tile[tx][ty + j]);
}

// ---------------------------------------------------------------------------
// GEMM: C[m][n] = sum_k A_packed[m][k] * Bt[n][k] + bias[n].
// M=16384, N=1024, K=1024. 128x128 tile, BK=128, 4 waves, 16x16x32 MFMA.
// A comes straight from global in packed-fragment order (no LDS);
// B is staged in LDS (32 KB) with XOR-swizzled 16B granules (conflict-free).
// modes: 0=tanh->Db(norm)  1=sigmoid*(1-auxf[row])->Db(norm)
//        2=plain->Db(PACKED)  3=gelu->Db(PACKED)
//        4=(+auxb residual PACKED)->Df f32(norm)
//        5=dual: blockIdx.y>=8 -> {WinT1, sigmoid, Db2} else {WinT0, tanh, Db}
// ---------------------------------------------------------------------------
__global__ __launch_bounds__(256, 4) void gemm_k(
    const bf16* __restrict__ A, const bf16* __restrict__ Bt,
    const float* __restrict__ bias, const float* __restrict__ auxf,
    const bf16* __restrict__ auxb, bf16* __restrict__ Db,
    bf16* __restrict__ Db2, float* __restrict__ Df, const int mode)
{
    __shared__ alignas(16) bf16 Bs[128 * 128];   // [n][k], 32 KB

    const int tid  = threadIdx.x;
    const int wave = tid >> 6;
    const int lane = tid & 63;
    const int quad = lane >> 4;
    const int l16  = lane & 15;
    const int sw   = l16 & 7;
    const int wm   = wave & 1;
    const int wn   = wave >> 1;
    const int bm   = blockIdx.x * 128;

    int bn, emode;
    const bf16* Bte = Bt;
    const float* biase = bias;
    bf16* Dbe = Db;
    if (mode == 5) {
        const int mat = blockIdx.y >> 3;
        bn    = (blockIdx.y & 7) * 128;
        Bte   = Bt + ((size_t)mat << 20);
        biase = bias + (mat << 10);
        Dbe   = mat ? Db2 : Db;
        emode = mat ? 1 : 0;
    } else {
        bn = blockIdx.y * 128;
        emode = mode;
    }

    // B staging: chunk = 4 rows x 128 k = 1 KB. lane -> row lane>>4,
    // k-granule (lane&15)^(row&7). Chunk c rows = wave*32 + c*4.
    const int brow = lane >> 4;
    const int bgq  = lane & 15;
    const bf16* gB_e = Bte + (size_t)(bn + wave * 32 + brow) * 1024 + ((bgq ^ brow) << 3);
    const bf16* gB_o = Bte + (size_t)(bn + wave * 32 + brow) * 1024 + ((bgq ^ (4 + brow)) << 3);
    bf16* lB = &Bs[(wave * 32) * 128];

    // A fragment base pointers (packed layout, lane*16B)
    const bf16* pA[4];
#pragma unroll
    for (int t = 0; t < 4; ++t)
        pA[t] = A + (((size_t)(bm >> 4) + wm * 4 + t) << 14) + (lane << 3);

    floatx4 acc[4][4];
#pragma unroll
    for (int i = 0; i < 4; ++i)
#pragma unroll
        for (int j = 0; j < 4; ++j)
            acc[i][j] = (floatx4){0.f, 0.f, 0.f, 0.f};

    for (int k0 = 0; k0 < 1024; k0 += 128) {
        __syncthreads();
#pragma unroll
        for (int c = 0; c < 8; c += 2) {
            load_lds16(gB_e + ((size_t)c << 12) + k0, lB + (c << 9));
            load_lds16(gB_o + ((size_t)(c + 1) << 12) + k0, lB + ((c + 1) << 9));
        }
        __syncthreads();

#pragma unroll
        for (int kk = 0; kk < 4; ++kk) {
            bf16x8 af[4], bfr[4];
#pragma unroll
            for (int t = 0; t < 4; ++t)
                af[t] = *(const bf16x8*)(pA[t] + ((size_t)k0 << 4) + (kk << 9));
#pragma unroll
            for (int t = 0; t < 4; ++t)
                bfr[t] = *(const bf16x8*)&Bs[(size_t)(wn * 64 + t * 16 + l16) * 128
                                             + ((((kk << 2) + quad) ^ sw) << 3)];
#pragma unroll
            for (int tm = 0; tm < 4; ++tm)
#pragma unroll
                for (int tn = 0; tn < 4; ++tn)
                    acc[tm][tn] = __builtin_amdgcn_mfma_f32_16x16x32_bf16(
                        af[tm], bfr[tn], acc[tm][tn], 0, 0, 0);
        }
    }

    // epilogue. C/D layout: col = lane&15, row = quad*4 + reg (m89-verified)
    float bv[4];
#pragma unroll
    for (int tn = 0; tn < 4; ++tn)
        bv[tn] = biase[bn + wn * 64 + tn * 16 + l16];

#pragma unroll
    for (int tm = 0; tm < 4; ++tm) {
#pragma unroll
        for (int r = 0; r < 4; ++r) {
            const int gm = bm + wm * 64 + tm * 16 + quad * 4 + r;
            const size_t rowoff = (size_t)gm << 10;
            float rowmul = 1.f;
            if (emode == 1) rowmul = 1.f - auxf[gm];
#pragma unroll
            for (int tn = 0; tn < 4; ++tn) {
                const int gn = bn + wn * 64 + tn * 16 + l16;
                float val = acc[tm][tn][r] + bv[tn];
                if (emode == 0) {
                    val = tanhf(val);
                    Dbe[rowoff + gn] = f2bf(val);
                } else if (emode == 1) {
                    val = rowmul / (1.f + expf(-val));
                    Dbe[rowoff + gn] = f2bf(val);
                } else if (emode == 2) {
                    Dbe[paddr(gm, gn)] = f2bf(val);
                } else if (emode == 3) {
                    val = 0.5f * val * (1.f + erff(val * 0.70710678118654752f));
                    Dbe[paddr(gm, gn)] = f2bf(val);
                } else { // 4
                    val += bf2f(auxb[paddr(gm, gn)]);
                    Df[rowoff + gn] = val;
                }
            }
        }
    }
}

// ---------------------------------------------------------------------------
// Chunked linear-recurrence scan: h[t] = f[t]*h[t-1] + (1-f[t])*v[t].
// T=4096 in 64 chunks of 64; 4096 channels. v,f in normal [m][d] layout.
// ---------------------------------------------------------------------------
__global__ __launch_bounds__(256) void scan1_k(
    const bf16* __restrict__ v, const bf16* __restrict__ f,
    float* __restrict__ Ac, float* __restrict__ Bc)
{
    const int idx = blockIdx.x * 256 + threadIdx.x;
    const int ch = idx & 4095;
    const int c  = idx >> 12;
    const int b  = ch >> 10, d = ch & 1023;
    const size_t base = ((size_t)(b * 4096 + c * 64) << 10) + d;
    float a = 1.f, hb = 0.f;
#pragma unroll 8
    for (int i = 0; i < 64; ++i) {
        const size_t o = base + ((size_t)i << 10);
        const float ft = bf2f(f[o]);
        const float vt = bf2f(v[o]);
        hb = fmaf(ft, hb, (1.f - ft) * vt);
        a *= ft;
    }
    Ac[c * 4096 + ch] = a;
    Bc[c * 4096 + ch] = hb;
}

__global__ __launch_bounds__(256) void scanmid_k(
    const float* __restrict__ Ac, const float* __restrict__ Bc,
    const float* __restrict__ hidden, float* __restrict__ Hin)
{
    const int ch = blockIdx.x * 256 + threadIdx.x;
    float h = hidden[ch];
#pragma unroll 8
    for (int c = 0; c < 64; ++c) {
        Hin[c * 4096 + ch] = h;
        h = fmaf(Ac[c * 4096 + ch], h, Bc[c * 4096 + ch]);
    }
}

// writes hs in PACKED layout (A operand of the Wout GEMM)
__global__ __launch_bounds__(256) void scan2_k(
    const bf16* __restrict__ v, const bf16* __restrict__ f,
    const float* __restrict__ Hin, bf16* __restrict__ hs,
    float* __restrict__ hT)
{
    const int idx = blockIdx.x * 256 + threadIdx.x;
    const int ch = idx & 4095;
    const int c  = idx >> 12;
    const int b  = ch >> 10, d = ch & 1023;
    const size_t base = ((size_t)(b * 4096 + c * 64) << 10) + d;
    const int m0 = b * 4096 + c * 64;
    const size_t dpart = ((size_t)(d >> 5) << 9) + (((d >> 3) & 3) << 7) + (d & 7);
    float h = Hin[c * 4096 + ch];
#pragma unroll 8
    for (int i = 0; i < 64; ++i) {
        const size_t o = base + ((size_t)i << 10);
        const float ft = bf2f(f[o]);
        const float vt = bf2f(v[o]);
        h = fmaf(ft, h, (1.f - ft) * vt);
        const int m = m0 + i;
        hs[((size_t)(m >> 4) << 14) + dpart + ((m & 15) << 3)] = f2bf(h);
    }
    if (c == 63) hT[ch] = h;
}

// ---------------------------------------------------------------------------
// LayerNorm over D=1024 (f32 in-place on d_out), one block per row.
// ---------------------------------------------------------------------------
__global__ __launch_bounds__(256) void ln_k(
    float* __restrict__ s, const float* __restrict__ g,
    const float* __restrict__ b)
{
    const int row = blockIdx.x;
    const int tid = threadIdx.x;
    const size_t off = (size_t)row << 10;
    const float4 xv = ((const float4*)(s + off))[tid];
    float sum = xv.x + xv.y + xv.z + xv.w;
    float sq  = xv.x * xv.x + xv.y * xv.y + xv.z * xv.z + xv.w * xv.w;
#pragma unroll
    for (int o = 32; o > 0; o >>= 1) {
        sum += __shfl_down(sum, o, 64);
        sq  += __shfl_down(sq,  o, 64);
    }
    __shared__ float s1[4], s2[4];
    if ((tid & 63) == 0) { s1[tid >> 6] = sum; s2[tid >> 6] = sq; }
    __syncthreads();
    sum = s1[0] + s1[1] + s1[2] + s1[3];
    sq  = s2[0] + s2[1] + s2[2] + s2[3];
    const float mean = sum * (1.f / 1024.f);
    const float var  = sq * (1.f / 1024.f) - mean * mean;
    const float rstd = rsqrtf(var + 1e-5f);
    const float4 gv = ((const float4*)g)[tid];
    const float4 bv = ((const float4*)b)[tid];
    float4 y;
    y.x = (xv.x - mean) * rstd * gv.x + bv.x;
    y.y = (xv.y - mean) * rstd * gv.y + bv.y;
    y.z = (xv.z - mean) * rstd * gv.z + bv.z;
    y.w = (xv.w - mean) * rstd * gv.w + bv.w;
    ((float4*)(s + off))[tid] = y;
}

// ---------------------------------------------------------------------------
extern "C" void kernel_launch(void* const* d_in, const int* in_sizes, int n_in,
                              void* d_out, int out_size, void* d_ws, size_t ws_size,
                              hipStream_t stream)
{
    const float* x         = (const float*)d_in[0];
    const float* hidden    = (const float*)d_in[1];
    const float* rnn_start = (const float*)d_in[2];
    const float* Win       = (const float*)d_in[3];
    const float* bin_      = (const float*)d_in[4];
    const float* Wout      = (const float*)d_in[5];
    const float* bout      = (const float*)d_in[6];
    const float* W1        = (const float*)d_in[7];
    const float* b1        = (const float*)d_in[8];
    const float* W2        = (const float*)d_in[9];
    const float* b2        = (const float*)d_in[10];
    const float* ln_g      = (const float*)d_in[11];
    const float* ln_b      = (const float*)d_in[12];
    float* out = (float*)d_out;                // out(16777216 f32) ++ hidden_new(4096 f32)
    float* hT  = out + (1u << 24);

    char* p = (char*)d_ws;
    bf16* Wt    = (bf16*)p;                    p += 5ull * (1u << 20) * sizeof(bf16);
    bf16* slotA = (bf16*)p;                    p += (1ull << 24) * sizeof(bf16);  // xb(packed), later hs(packed)
    bf16* slotB = (bf16*)p;                    p += (1ull << 24) * sizeof(bf16);  // v(norm),  later outp(packed)
    bf16* slotC = (bf16*)p;                    p += (1ull << 24) * sizeof(bf16);  // f(norm),  later x_(packed)
    float* Ac  = (float*)p;                    p += (1ull << 18) * sizeof(float);
    float* Bc  = (float*)p;                    p += (1ull << 18) * sizeof(float);
    float* Hin = (float*)p;                    p += (1ull << 18) * sizeof(float);

    bf16* WoutT = Wt + 2u * (1u << 20);
    bf16* W1T   = Wt + 3u * (1u << 20);
    bf16* W2T   = Wt + 4u * (1u << 20);

    packx_k<<<dim3(1024, 4), 256, 0, stream>>>(x, slotA);
    trc_k<<<dim3(32, 32, 5), 256, 0, stream>>>(Win, Win + (1u << 20), Wout, W1, W2, Wt);

    // dual GEMM: v -> slotB (norm), f -> slotC (norm)
    gemm_k<<<dim3(128, 16), 256, 0, stream>>>(slotA, Wt, bin_, rnn_start, nullptr,
                                              slotB, slotC, nullptr, 5);

    scan1_k<<<1024, 256, 0, stream>>>(slotB, slotC, Ac, Bc);
    scanmid_k<<<16, 256, 0, stream>>>(Ac, Bc, hidden, Hin);
    scan2_k<<<1024, 256, 0, stream>>>(slotB, slotC, Hin, slotA, hT);  // hs packed

    // outp = hs@Wout + bout (packed -> slotB); x_ = gelu(outp@W1+b1) (packed -> slotC);
    // s = x_@W2 + b2 + outp -> f32 d_out
    gemm_k<<<dim3(128, 8), 256, 0, stream>>>(slotA, WoutT, bout, nullptr, nullptr,
                                             slotB, nullptr, nullptr, 2);
    gemm_k<<<dim3(128, 8), 256, 0, stream>>>(slotB, W1T,   b1,   nullptr, nullptr,
                                             slotC, nullptr, nullptr, 3);
    gemm_k<<<dim3(128, 8), 256, 0, stream>>>(slotC, W2T,   b2,   nullptr, slotB,
                                             nullptr, nullptr, out, 4);

    ln_k<<<16384, 256, 0, stream>>>(out, ln_g, ln_b);
}